// Round 4
// baseline (24979.880 us; speedup 1.0000x reference)
//
#include <hip/hip_runtime.h>

// LSTM B=32 T=2048 I=H=512. out = h_T [1,32,512] f32.
// p1: x_proj chunk GEMM (bf16 MFMA) -> xp[t_local*32+b][4H] bf16 (bias folded).
// p2: persistent recurrence, 32 blocks x 4 waves, ZERO barriers. Wave (k,w) owns
//   units U=k*16+w*4..+4, all 4 gates (rows unit*4+gate). W_hh frags in VGPRs.
//   h exchanged as tagged words (bf16<<16 | step) in 4-slot rotation; consumers
//   bulk-load A-frags, tag-verify, retry-with-fence. Producers are drain-free.

#define T_FULL 2048
#define CHUNK  256
#define NCHUNK 8
#define NBLK   32

typedef float  f32x4 __attribute__((ext_vector_type(4)));
typedef short  s16x8 __attribute__((ext_vector_type(8)));
typedef unsigned int u32;
typedef u32    u32x4 __attribute__((ext_vector_type(4)));

#define MFMA16(a,b,c) __builtin_amdgcn_mfma_f32_16x16x32_bf16((a),(b),(c),0,0,0)

__device__ inline unsigned short f2bf(float f){
  unsigned u = __builtin_bit_cast(unsigned, f);
  u += 0x7fffu + ((u>>16)&1u);          // RNE
  return (unsigned short)(u>>16);
}
__device__ inline float bf2f(unsigned short s){
  unsigned u = ((unsigned)s)<<16;
  return __builtin_bit_cast(float, u);
}
__device__ inline float sigmoid_(float x){
  x = fminf(fmaxf(x,-30.f),30.f);
  return 1.f/(1.f + __expf(-x));
}
__device__ inline float tanh_(float x){
  x = fminf(fmaxf(x,-15.f),15.f);
  float e = __expf(2.f*x);
  return (e-1.f)/(e+1.f);
}

// ---------------- Phase 1: x_proj chunk GEMM ----------------
__global__ __launch_bounds__(256) void lstm_p1(
    const float* __restrict__ x, const float* __restrict__ Wih,
    const float* __restrict__ bih, const float* __restrict__ bhh,
    unsigned short* __restrict__ xp, int t0)
{
  __shared__ __align__(16) unsigned short At[64*136];
  __shared__ __align__(16) unsigned short Bt[64*136];
  const int tid = threadIdx.x, lane = tid&63, w = tid>>6;
  const int l15 = lane&15, l4 = lane>>4;
  const int n0 = blockIdx.x*64, m0 = blockIdx.y*64;
  const int mbase = (w&1)*32, nbase = (w>>1)*32;

  f32x4 acc[2][2];
  #pragma unroll
  for (int mi=0; mi<2; ++mi)
    #pragma unroll
    for (int ni=0; ni<2; ++ni)
      acc[mi][ni] = (f32x4){0.f,0.f,0.f,0.f};

  for (int kb=0; kb<4; ++kb){
    #pragma unroll
    for (int it=0; it<4; ++it){
      int grp = it*256 + tid;            // 0..1023
      int row = grp>>4, c8 = (grp&15)*8; // 16 groups of 8 per row
      {
        int m = m0 + row;
        size_t t = (size_t)t0 + (m>>5), b = (size_t)(m&31);
        const float* src = x + ((b*2048 + t)<<9) + kb*128 + c8;
        f32x4 v0 = *(const f32x4*)src, v1 = *(const f32x4*)(src+4);
        unsigned short* d = &At[row*136 + c8];
        d[0]=f2bf(v0[0]); d[1]=f2bf(v0[1]); d[2]=f2bf(v0[2]); d[3]=f2bf(v0[3]);
        d[4]=f2bf(v1[0]); d[5]=f2bf(v1[1]); d[6]=f2bf(v1[2]); d[7]=f2bf(v1[3]);
      }
      {
        const float* src = Wih + (size_t)(n0+row)*512 + kb*128 + c8;
        f32x4 v0 = *(const f32x4*)src, v1 = *(const f32x4*)(src+4);
        unsigned short* d = &Bt[row*136 + c8];
        d[0]=f2bf(v0[0]); d[1]=f2bf(v0[1]); d[2]=f2bf(v0[2]); d[3]=f2bf(v0[3]);
        d[4]=f2bf(v1[0]); d[5]=f2bf(v1[1]); d[6]=f2bf(v1[2]); d[7]=f2bf(v1[3]);
      }
    }
    __syncthreads();
    #pragma unroll
    for (int ks=0; ks<4; ++ks){
      s16x8 af0 = *(const s16x8*)&At[(mbase+   l15)*136 + ks*32 + l4*8];
      s16x8 af1 = *(const s16x8*)&At[(mbase+16+l15)*136 + ks*32 + l4*8];
      s16x8 bf0 = *(const s16x8*)&Bt[(nbase+   l15)*136 + ks*32 + l4*8];
      s16x8 bf1 = *(const s16x8*)&Bt[(nbase+16+l15)*136 + ks*32 + l4*8];
      acc[0][0] = MFMA16(af0,bf0,acc[0][0]);
      acc[0][1] = MFMA16(af0,bf1,acc[0][1]);
      acc[1][0] = MFMA16(af1,bf0,acc[1][0]);
      acc[1][1] = MFMA16(af1,bf1,acc[1][1]);
    }
    __syncthreads();
  }
  #pragma unroll
  for (int ni=0; ni<2; ++ni){
    int col = n0 + nbase + ni*16 + l15;
    float bias = bih[col] + bhh[col];
    #pragma unroll
    for (int mi=0; mi<2; ++mi){
      #pragma unroll
      for (int r=0; r<4; ++r){
        int mrow = m0 + mbase + mi*16 + l4*4 + r;
        xp[(size_t)mrow*2048 + col] = f2bf(acc[mi][ni][r] + bias);
      }
    }
  }
}

// ---------------- Phase 2: recurrence (barrier-free tagged exchange) ---------
// H32: 4 slots x [32 batch][512 unit] u32 words, word = (bf16 h)<<16 | tag.
// h_t lives in slot t&3 with tag t. Step t: read tag t, publish tag t+1.
__global__ __launch_bounds__(256,1) void lstm_p2(
    const unsigned short* __restrict__ xp, const float* __restrict__ Whh,
    u32* __restrict__ H32, float* __restrict__ cst,
    float* __restrict__ out, int t0)
{
  const int k = blockIdx.x;
  const int tid = threadIdx.x;
  const int lane = tid & 63, w = tid >> 6;
  const int l15 = lane & 15, l4 = lane >> 4;
  const int u_local = l15 >> 2, g = l15 & 3;    // this lane's gate-row: unit,gate
  const int U = k*16 + w*4 + u_local;           // global hidden unit
  const int gcol = g*512 + U;                   // xp column for this gate-row

  // publish role: quad member q handles 2 batches
  const int q = g;
  const int mt_q = q >> 1, rr = (q & 1) * 2;
  const int bq = mt_q*16 + l4*4 + rr;

  // W_hh B-fragments: wave's 16 gate rows, row(n) = (n&3)*512 + k*16+w*4+(n>>2)
  s16x8 wf[16];
  {
    const float* wr = Whh + (size_t)(g*512 + U)*512;
    #pragma unroll
    for (int ks=0; ks<16; ++ks){
      const float* s = wr + ks*32 + l4*8;
      f32x4 v0 = *(const f32x4*)s, v1 = *(const f32x4*)(s+4);
      s16x8 tt;
      tt[0]=(short)f2bf(v0[0]); tt[1]=(short)f2bf(v0[1]);
      tt[2]=(short)f2bf(v0[2]); tt[3]=(short)f2bf(v0[3]);
      tt[4]=(short)f2bf(v1[0]); tt[5]=(short)f2bf(v1[1]);
      tt[6]=(short)f2bf(v1[2]); tt[7]=(short)f2bf(v1[3]);
      wf[ks] = tt;
    }
  }

  // c-state restore (quad-redundant: all 4 lanes hold all 8 (batch,unit) c's)
  float c[2][4];
  #pragma unroll
  for (int mt2=0; mt2<2; ++mt2)
    #pragma unroll
    for (int r=0; r<4; ++r)
      c[mt2][r] = cst[(size_t)(mt2*16 + l4*4 + r)*512 + U];

  for (int tt=0; tt<CHUNK; ++tt){
    const int t = t0 + tt;
    const u32 tagc = (u32)t, tagn = (u32)(t+1);
    const u32* Hs = H32 + (size_t)(t & 3)*16384;
    u32*       Hd = H32 + (size_t)((t+1) & 3)*16384;

    // xp gate inputs for this lane's gate-row x 8 batches (issue early)
    float xg[2][4];
    #pragma unroll
    for (int mt2=0; mt2<2; ++mt2)
      #pragma unroll
      for (int r=0; r<4; ++r)
        xg[mt2][r] = bf2f(xp[(size_t)(tt*32 + mt2*16 + l4*4 + r)*2048 + gcol]);

    // z = h_t @ Wslice^T  (tag-verified bundle per m-tile)
    f32x4 z[2];
    #pragma unroll
    for (int mt2=0; mt2<2; ++mt2){
      u32x4 A0[16], A1[16];
      u32 bad;
      do {
        __builtin_amdgcn_fence(__ATOMIC_ACQUIRE, "agent");
        const u32* rowp = Hs + (mt2*16 + l15)*512 + l4*8;
        #pragma unroll
        for (int ks=0; ks<16; ++ks){
          A0[ks] = *(const u32x4*)(rowp + ks*32);
          A1[ks] = *(const u32x4*)(rowp + ks*32 + 4);
        }
        bad = 0;
        #pragma unroll
        for (int ks=0; ks<16; ++ks){
          #pragma unroll
          for (int j=0; j<4; ++j){
            bad |= (A0[ks][j] ^ tagc);
            bad |= (A1[ks][j] ^ tagc);
          }
        }
        bad &= 0xffffu;
      } while (__any(bad != 0));

      f32x4 acc = (f32x4){0.f,0.f,0.f,0.f};
      #pragma unroll
      for (int ks=0; ks<16; ++ks){
        u32x4 p;
        p[0] = (A0[ks][0] >> 16) | (A0[ks][1] & 0xffff0000u);
        p[1] = (A0[ks][2] >> 16) | (A0[ks][3] & 0xffff0000u);
        p[2] = (A1[ks][0] >> 16) | (A1[ks][1] & 0xffff0000u);
        p[3] = (A1[ks][2] >> 16) | (A1[ks][3] & 0xffff0000u);
        s16x8 af = __builtin_bit_cast(s16x8, p);
        acc = MFMA16(af, wf[ks], acc);
      }
      z[mt2] = acc;
    }

    // gates: quad shfl exchange (lane's z is gate g for its unit)
    float hv[2][4];
    #pragma unroll
    for (int mt2=0; mt2<2; ++mt2){
      #pragma unroll
      for (int r=0; r<4; ++r){
        float v = z[mt2][r] + xg[mt2][r];
        float vi = __shfl_xor(v, g    );
        float vf = __shfl_xor(v, g ^ 1);
        float vg = __shfl_xor(v, g ^ 2);
        float vo = __shfl_xor(v, g ^ 3);
        float ii = sigmoid_(vi), ff = sigmoid_(vf);
        float gg = tanh_(vg),    oo = sigmoid_(vo);
        float cc = ff*c[mt2][r] + ii*gg;
        c[mt2][r] = cc;
        hv[mt2][r] = oo * tanh_(cc);
      }
    }

    // publish h_{t+1}: 2 tagged words per lane (drain-free, fire & proceed)
    {
      float ha0 = (q&1) ? hv[0][2] : hv[0][0];
      float ha1 = (q&1) ? hv[0][3] : hv[0][1];
      float hb0 = (q&1) ? hv[1][2] : hv[1][0];
      float hb1 = (q&1) ? hv[1][3] : hv[1][1];
      float h0 = (q>>1) ? hb0 : ha0;
      float h1 = (q>>1) ? hb1 : ha1;
      u32 w0 = ((u32)f2bf(h0) << 16) | tagn;
      u32 w1 = ((u32)f2bf(h1) << 16) | tagn;
      __hip_atomic_store(&Hd[(size_t)(bq  )*512 + U], w0,
                         __ATOMIC_RELAXED, __HIP_MEMORY_SCOPE_AGENT);
      __hip_atomic_store(&Hd[(size_t)(bq+1)*512 + U], w1,
                         __ATOMIC_RELAXED, __HIP_MEMORY_SCOPE_AGENT);
      if (t == T_FULL-1){
        out[(size_t)(bq  )*512 + U] = h0;
        out[(size_t)(bq+1)*512 + U] = h1;
      }
    }
  }

  // c-state save (this lane's 2 assigned rows)
  {
    float ca0 = (q&1) ? c[0][2] : c[0][0];
    float ca1 = (q&1) ? c[0][3] : c[0][1];
    float cb0 = (q&1) ? c[1][2] : c[1][0];
    float cb1 = (q&1) ? c[1][3] : c[1][1];
    float c0s = (q>>1) ? cb0 : ca0;
    float c1s = (q>>1) ? cb1 : ca1;
    cst[(size_t)(bq  )*512 + U] = c0s;
    cst[(size_t)(bq+1)*512 + U] = c1s;
  }
}

// ---------------- launch ----------------
extern "C" void kernel_launch(void* const* d_in, const int* in_sizes, int n_in,
                              void* d_out, int out_size, void* d_ws, size_t ws_size,
                              hipStream_t stream)
{
  const float* x   = (const float*)d_in[0];
  const float* Wih = (const float*)d_in[1];
  const float* Whh = (const float*)d_in[2];
  const float* bih = (const float*)d_in[3];
  const float* bhh = (const float*)d_in[4];
  float* out = (float*)d_out;

  char* ws = (char*)d_ws;
  const size_t XP_BYTES = (size_t)CHUNK*32*2048*2;                 // 33,554,432
  unsigned short* xp  = (unsigned short*)ws;
  u32*            H32 = (u32*)(ws + XP_BYTES);                     // 4*64KB = 262144
  float*          cst = (float*)(ws + XP_BYTES + 262144);          // 64KB

  // zero tagged H buffer (tag0 == h_0 == 0) + c-state; every launch (replay-safe)
  (void)hipMemsetAsync(H32, 0, 262144 + 65536, stream);

  for (int c=0; c<NCHUNK; ++c){
    int t0 = c*CHUNK;
    lstm_p1<<<dim3(32, CHUNK*32/64), 256, 0, stream>>>(x, Wih, bih, bhh, xp, t0);
    lstm_p2<<<NBLK, 256, 0, stream>>>(xp, Whh, H32, cst, out, t0);
  }
}

// Round 5
// 15865.866 us; speedup vs baseline: 1.5744x; 1.5744x over previous
//
#include <hip/hip_runtime.h>

// LSTM B=32 T=2048 I=H=512. out = h_T [1,32,512] f32.
// p1: x_proj GEMM for chunk 0 only. fused: blocks 0..31 = recurrence chunk c
//   (block k owns units [16k,16k+16), rows unit*4+gate, W_hh frags in VGPRs;
//   tagged-H exchange: word=(bf16<<16|step), 4-slot rotation, block-level
//   fetch+verify into double-buffered swizzled LDS, drain-free producers);
//   blocks 32..255 = x_proj GEMM for chunk c+1 (ping-pong xp buffers).

#define T_FULL 2048
#define CHUNK  128
#define NCHUNK 16
#define NBLK   32
#define NGEMM  224   // 256 - NBLK

typedef float  f32x4 __attribute__((ext_vector_type(4)));
typedef short  s16x8 __attribute__((ext_vector_type(8)));
typedef unsigned int u32;
typedef u32    u32x4 __attribute__((ext_vector_type(4)));

#define MFMA16(a,b,c) __builtin_amdgcn_mfma_f32_16x16x32_bf16((a),(b),(c),0,0,0)

__device__ inline unsigned short f2bf(float f){
  unsigned u = __builtin_bit_cast(unsigned, f);
  u += 0x7fffu + ((u>>16)&1u);          // RNE
  return (unsigned short)(u>>16);
}
__device__ inline float bf2f(unsigned short s){
  unsigned u = ((unsigned)s)<<16;
  return __builtin_bit_cast(float, u);
}
__device__ inline float sigmoid_(float x){
  x = fminf(fmaxf(x,-30.f),30.f);
  return 1.f/(1.f + __expf(-x));
}
__device__ inline float tanh_(float x){
  x = fminf(fmaxf(x,-15.f),15.f);
  float e = __expf(2.f*x);
  return (e-1.f)/(e+1.f);
}

// ---------------- x_proj GEMM tile (64M x 64N, K=512) ----------------
// smem: At at +0 (17408B), Bt at +17408 (17408B).
__device__ void gemm_tile(const float* __restrict__ x, const float* __restrict__ Wih,
                          const float* __restrict__ bih, const float* __restrict__ bhh,
                          unsigned short* __restrict__ xp, int t0, int nx, int ny,
                          char* smem)
{
  unsigned short* At = (unsigned short*)smem;
  unsigned short* Bt = (unsigned short*)(smem + 17408);
  const int tid = threadIdx.x, lane = tid&63, w = tid>>6;
  const int l15 = lane&15, l4 = lane>>4;
  const int n0 = nx*64, m0 = ny*64;
  const int mbase = (w&1)*32, nbase = (w>>1)*32;

  f32x4 acc[2][2];
  #pragma unroll
  for (int mi=0; mi<2; ++mi)
    #pragma unroll
    for (int ni=0; ni<2; ++ni)
      acc[mi][ni] = (f32x4){0.f,0.f,0.f,0.f};

  for (int kb=0; kb<4; ++kb){
    #pragma unroll
    for (int it=0; it<4; ++it){
      int grp = it*256 + tid;            // 0..1023
      int row = grp>>4, c8 = (grp&15)*8; // 16 groups of 8 per row
      {
        int m = m0 + row;
        size_t t = (size_t)t0 + (m>>5), b = (size_t)(m&31);
        const float* src = x + ((b*2048 + t)<<9) + kb*128 + c8;
        f32x4 v0 = *(const f32x4*)src, v1 = *(const f32x4*)(src+4);
        unsigned short* d = &At[row*136 + c8];
        d[0]=f2bf(v0[0]); d[1]=f2bf(v0[1]); d[2]=f2bf(v0[2]); d[3]=f2bf(v0[3]);
        d[4]=f2bf(v1[0]); d[5]=f2bf(v1[1]); d[6]=f2bf(v1[2]); d[7]=f2bf(v1[3]);
      }
      {
        const float* src = Wih + (size_t)(n0+row)*512 + kb*128 + c8;
        f32x4 v0 = *(const f32x4*)src, v1 = *(const f32x4*)(src+4);
        unsigned short* d = &Bt[row*136 + c8];
        d[0]=f2bf(v0[0]); d[1]=f2bf(v0[1]); d[2]=f2bf(v0[2]); d[3]=f2bf(v0[3]);
        d[4]=f2bf(v1[0]); d[5]=f2bf(v1[1]); d[6]=f2bf(v1[2]); d[7]=f2bf(v1[3]);
      }
    }
    __syncthreads();
    #pragma unroll
    for (int ks=0; ks<4; ++ks){
      s16x8 af0 = *(const s16x8*)&At[(mbase+   l15)*136 + ks*32 + l4*8];
      s16x8 af1 = *(const s16x8*)&At[(mbase+16+l15)*136 + ks*32 + l4*8];
      s16x8 bf0 = *(const s16x8*)&Bt[(nbase+   l15)*136 + ks*32 + l4*8];
      s16x8 bf1 = *(const s16x8*)&Bt[(nbase+16+l15)*136 + ks*32 + l4*8];
      acc[0][0] = MFMA16(af0,bf0,acc[0][0]);
      acc[0][1] = MFMA16(af0,bf1,acc[0][1]);
      acc[1][0] = MFMA16(af1,bf0,acc[1][0]);
      acc[1][1] = MFMA16(af1,bf1,acc[1][1]);
    }
    __syncthreads();
  }
  #pragma unroll
  for (int ni=0; ni<2; ++ni){
    int col = n0 + nbase + ni*16 + l15;
    float bias = bih[col] + bhh[col];
    #pragma unroll
    for (int mi=0; mi<2; ++mi){
      #pragma unroll
      for (int r=0; r<4; ++r){
        int mrow = m0 + mbase + mi*16 + l4*4 + r;
        xp[(size_t)mrow*2048 + col] = f2bf(acc[mi][ni][r] + bias);
      }
    }
  }
}

// ---------------- Phase 1 standalone (chunk 0) ----------------
__global__ __launch_bounds__(256) void lstm_p1(
    const float* __restrict__ x, const float* __restrict__ Wih,
    const float* __restrict__ bih, const float* __restrict__ bhh,
    unsigned short* __restrict__ xp, int t0)
{
  __shared__ __align__(16) char smem[34816];
  gemm_tile(x, Wih, bih, bhh, xp, t0, blockIdx.x, blockIdx.y, smem);
}

// ---------------- Fused: recurrence (blocks 0..31) + next-chunk GEMM ---------
__global__ __launch_bounds__(256,1) void lstm_fused(
    const unsigned short* __restrict__ xp_cur,
    const float* __restrict__ x, const float* __restrict__ Wih,
    const float* __restrict__ bih, const float* __restrict__ bhh,
    unsigned short* __restrict__ xp_next, const float* __restrict__ Whh,
    u32* __restrict__ H32, float* __restrict__ cst, float* __restrict__ out,
    int t0, int do_gemm)
{
  __shared__ __align__(16) char smem[65536];  // recur: 2x32KB H dbuf; gemm: At/Bt
  const int bid = blockIdx.x;

  if (bid >= NBLK){
    if (do_gemm){
      const int t0n = t0 + CHUNK;
      for (int tile = bid - NBLK; tile < 32*(CHUNK*32/64); tile += NGEMM)
        gemm_tile(x, Wih, bih, bhh, xp_next, t0n, tile & 31, tile >> 5, smem);
    }
    return;
  }

  const int k = bid;
  const int tid = threadIdx.x;
  const int lane = tid & 63, w = tid >> 6;
  const int l15 = lane & 15, l4 = lane >> 4;
  const int g = l15 & 3;                        // lane's gate
  const int U = k*16 + w*4 + (l15 >> 2);        // lane's global hidden unit
  const int gcol = g*512 + U;                   // xp column of this gate-row
  const int q = g;                              // quad member: which 2 batches to publish
  const int bq = (q>>1)*16 + l4*4 + (q&1)*2;

  // W_hh B-fragments: wave's 16 gate rows, n=l15 -> W row g*512+U
  s16x8 wf[16];
  {
    const float* wr = Whh + (size_t)(g*512 + U)*512;
    #pragma unroll
    for (int ks=0; ks<16; ++ks){
      const float* s = wr + ks*32 + l4*8;
      f32x4 v0 = *(const f32x4*)s, v1 = *(const f32x4*)(s+4);
      s16x8 tt;
      tt[0]=(short)f2bf(v0[0]); tt[1]=(short)f2bf(v0[1]);
      tt[2]=(short)f2bf(v0[2]); tt[3]=(short)f2bf(v0[3]);
      tt[4]=(short)f2bf(v1[0]); tt[5]=(short)f2bf(v1[1]);
      tt[6]=(short)f2bf(v1[2]); tt[7]=(short)f2bf(v1[3]);
      wf[ks] = tt;
    }
  }

  // c-state restore (quad-redundant)
  float c[2][4];
  #pragma unroll
  for (int mt2=0; mt2<2; ++mt2)
    #pragma unroll
    for (int r=0; r<4; ++r)
      c[mt2][r] = cst[(size_t)(mt2*16 + l4*4 + r)*512 + U];

  // staging geometry: thread covers batch tid>>3, units [(tid&7)*64, +64)
  const int rbase = (tid>>3) << 10;             // byte row base in LDS (1KB/row)
  const u32 rsw  = (u32)(((tid>>3)&7) << 4);    // XOR swizzle for this row
  const int u0b  = (tid&7)*128;                 // byte col base

  for (int tt=0; tt<CHUNK; ++tt){
    const int t = t0 + tt;
    const u32 tagc = (u32)t, tagn = (u32)(t+1);
    const u32* Hs = H32 + (size_t)(t & 3)*16384;
    u32*       Hd = H32 + (size_t)((t+1) & 3)*16384;
    char* Hl = smem + (size_t)(t & 1)*32768;

    // xp gate inputs (issue early; 8 scalar bf16 loads)
    float xg[2][4];
    #pragma unroll
    for (int mt2=0; mt2<2; ++mt2)
      #pragma unroll
      for (int r=0; r<4; ++r)
        xg[mt2][r] = bf2f(xp_cur[(size_t)(tt*32 + mt2*16 + l4*4 + r)*2048 + gcol]);

    // fetch tagged H (256B/thread), verify, unpack->LDS, block vote
    {
      const u32* myp = Hs + (tid << 6);
      for (;;){
        u32x4 Wd[16];
        #pragma unroll
        for (int i=0; i<16; ++i) Wd[i] = *(const u32x4*)(myp + i*4);
        u32 bad = 0;
        #pragma unroll
        for (int i=0; i<16; ++i)
          bad |= (Wd[i][0]^tagc) | (Wd[i][1]^tagc) | (Wd[i][2]^tagc) | (Wd[i][3]^tagc);
        bad &= 0xffffu;
        #pragma unroll
        for (int j=0; j<8; ++j){
          u32x4 o;
          o[0] = (Wd[2*j  ][0]>>16) | (Wd[2*j  ][1] & 0xffff0000u);
          o[1] = (Wd[2*j  ][2]>>16) | (Wd[2*j  ][3] & 0xffff0000u);
          o[2] = (Wd[2*j+1][0]>>16) | (Wd[2*j+1][1] & 0xffff0000u);
          o[3] = (Wd[2*j+1][2]>>16) | (Wd[2*j+1][3] & 0xffff0000u);
          *(u32x4*)(Hl + (rbase | (u32)((u32)(u0b + j*16) ^ rsw))) = o;
        }
        if (__syncthreads_count((int)(bad != 0)) == 0) break;
        __builtin_amdgcn_fence(__ATOMIC_ACQUIRE, "agent");
      }
    }

    // z = h_t @ Wslice^T : 2 m-tiles x 16 ks, A from swizzled LDS
    f32x4 z[2];
    #pragma unroll
    for (int mt2=0; mt2<2; ++mt2){
      const int row = mt2*16 + l15;
      const int swz = (row&7)<<4, rb = row<<10;
      f32x4 acc = (f32x4){0.f,0.f,0.f,0.f};
      #pragma unroll
      for (int ks=0; ks<16; ++ks){
        int cb = ks*64 + l4*16;
        s16x8 af = *(const s16x8*)(Hl + (rb | (cb ^ swz)));
        acc = MFMA16(af, wf[ks], acc);
      }
      z[mt2] = acc;
    }

    // gates: quad shfl exchange (lane holds gate g of its unit)
    float hv[2][4];
    #pragma unroll
    for (int mt2=0; mt2<2; ++mt2){
      #pragma unroll
      for (int r=0; r<4; ++r){
        float v = z[mt2][r] + xg[mt2][r];
        float vi = __shfl_xor(v, g    );
        float vf = __shfl_xor(v, g ^ 1);
        float vg = __shfl_xor(v, g ^ 2);
        float vo = __shfl_xor(v, g ^ 3);
        float ii = sigmoid_(vi), ff = sigmoid_(vf);
        float gg = tanh_(vg),    oo = sigmoid_(vo);
        float cc = ff*c[mt2][r] + ii*gg;
        c[mt2][r] = cc;
        hv[mt2][r] = oo * tanh_(cc);
      }
    }

    // publish h_{t+1}: 2 tagged words per lane, drain-free
    {
      float ha0 = (q&1) ? hv[0][2] : hv[0][0];
      float ha1 = (q&1) ? hv[0][3] : hv[0][1];
      float hb0 = (q&1) ? hv[1][2] : hv[1][0];
      float hb1 = (q&1) ? hv[1][3] : hv[1][1];
      float h0 = (q>>1) ? hb0 : ha0;
      float h1 = (q>>1) ? hb1 : ha1;
      u32 w0 = ((u32)f2bf(h0) << 16) | tagn;
      u32 w1 = ((u32)f2bf(h1) << 16) | tagn;
      __hip_atomic_store(&Hd[(size_t)(bq  )*512 + U], w0,
                         __ATOMIC_RELAXED, __HIP_MEMORY_SCOPE_AGENT);
      __hip_atomic_store(&Hd[(size_t)(bq+1)*512 + U], w1,
                         __ATOMIC_RELAXED, __HIP_MEMORY_SCOPE_AGENT);
      if (t == T_FULL-1){
        out[(size_t)(bq  )*512 + U] = h0;
        out[(size_t)(bq+1)*512 + U] = h1;
      }
    }
  }

  // c-state save (lane's 2 assigned batches)
  {
    float ca0 = (q&1) ? c[0][2] : c[0][0];
    float ca1 = (q&1) ? c[0][3] : c[0][1];
    float cb0 = (q&1) ? c[1][2] : c[1][0];
    float cb1 = (q&1) ? c[1][3] : c[1][1];
    float c0s = (q>>1) ? cb0 : ca0;
    float c1s = (q>>1) ? cb1 : ca1;
    cst[(size_t)(bq  )*512 + U] = c0s;
    cst[(size_t)(bq+1)*512 + U] = c1s;
  }
}

// ---------------- launch ----------------
extern "C" void kernel_launch(void* const* d_in, const int* in_sizes, int n_in,
                              void* d_out, int out_size, void* d_ws, size_t ws_size,
                              hipStream_t stream)
{
  const float* x   = (const float*)d_in[0];
  const float* Wih = (const float*)d_in[1];
  const float* Whh = (const float*)d_in[2];
  const float* bih = (const float*)d_in[3];
  const float* bhh = (const float*)d_in[4];
  float* out = (float*)d_out;

  char* ws = (char*)d_ws;
  const size_t XPB = (size_t)CHUNK*32*2048*2;          // 16,777,216 per buffer
  unsigned short* xp0 = (unsigned short*)ws;
  unsigned short* xp1 = (unsigned short*)(ws + XPB);
  u32*            H32 = (u32*)(ws + 2*XPB);            // 4*64KB = 262144
  float*          cst = (float*)(ws + 2*XPB + 262144); // 64KB

  // zero tagged H (tag0 == h_0 == 0) + c-state; every launch (replay-safe)
  (void)hipMemsetAsync(H32, 0, 262144 + 65536, stream);

  lstm_p1<<<dim3(32, CHUNK*32/64), 256, 0, stream>>>(x, Wih, bih, bhh, xp0, 0);

  for (int c=0; c<NCHUNK; ++c){
    unsigned short* xc = (c & 1) ? xp1 : xp0;
    unsigned short* xn = (c & 1) ? xp0 : xp1;
    lstm_fused<<<256, 256, 0, stream>>>(xc, x, Wih, bih, bhh, xn, Whh,
                                        H32, cst, out, c*CHUNK, (c < NCHUNK-1) ? 1 : 0);
  }
}

// Round 6
// 13640.770 us; speedup vs baseline: 1.8313x; 1.1631x over previous
//
#include <hip/hip_runtime.h>

// LSTM B=32 T=2048 I=H=512. out = h_T [1,32,512] f32.
// p1: x_proj chunk GEMM (bf16 MFMA) -> xp[t_local*32+b][4H] bf16 (bias folded).
// p2: persistent recurrence, 32 blocks. Block k owns units [16k,16k+16),
//   gate rows unit*4+gate, W_hh frags in VGPRs. Tagged-H exchange:
//   word=(bf16<<16|step), 4-slot rotation, drain-free producers.
//   Consumer: wave0 probes 32 sentinels (relaxed atomic, no fence), then one
//   fenced bulk fetch (one row/wave/iter, conflict-free swizzled LDS stage),
//   verify-all-tags + syncthreads_count retry loop. Quad-shfl gates.

#define T_FULL 2048
#define CHUNK  256
#define NCHUNK 8
#define NBLK   32

typedef float  f32x4 __attribute__((ext_vector_type(4)));
typedef short  s16x8 __attribute__((ext_vector_type(8)));
typedef unsigned int u32;
typedef u32    u32x4 __attribute__((ext_vector_type(4)));

#define MFMA16(a,b,c) __builtin_amdgcn_mfma_f32_16x16x32_bf16((a),(b),(c),0,0,0)

__device__ inline unsigned short f2bf(float f){
  unsigned u = __builtin_bit_cast(unsigned, f);
  u += 0x7fffu + ((u>>16)&1u);          // RNE
  return (unsigned short)(u>>16);
}
__device__ inline float bf2f(unsigned short s){
  unsigned u = ((unsigned)s)<<16;
  return __builtin_bit_cast(float, u);
}
__device__ inline float sigmoid_(float x){
  x = fminf(fmaxf(x,-30.f),30.f);
  return 1.f/(1.f + __expf(-x));
}
__device__ inline float tanh_(float x){
  x = fminf(fmaxf(x,-15.f),15.f);
  float e = __expf(2.f*x);
  return (e-1.f)/(e+1.f);
}

// ---------------- Phase 1: x_proj chunk GEMM ----------------
__global__ __launch_bounds__(256) void lstm_p1(
    const float* __restrict__ x, const float* __restrict__ Wih,
    const float* __restrict__ bih, const float* __restrict__ bhh,
    unsigned short* __restrict__ xp, int t0)
{
  __shared__ __align__(16) unsigned short At[64*136];
  __shared__ __align__(16) unsigned short Bt[64*136];
  const int tid = threadIdx.x, lane = tid&63, w = tid>>6;
  const int l15 = lane&15, l4 = lane>>4;
  const int n0 = blockIdx.x*64, m0 = blockIdx.y*64;
  const int mbase = (w&1)*32, nbase = (w>>1)*32;

  f32x4 acc[2][2];
  #pragma unroll
  for (int mi=0; mi<2; ++mi)
    #pragma unroll
    for (int ni=0; ni<2; ++ni)
      acc[mi][ni] = (f32x4){0.f,0.f,0.f,0.f};

  for (int kb=0; kb<4; ++kb){
    #pragma unroll
    for (int it=0; it<4; ++it){
      int grp = it*256 + tid;            // 0..1023
      int row = grp>>4, c8 = (grp&15)*8; // 16 groups of 8 per row
      {
        int m = m0 + row;
        size_t t = (size_t)t0 + (m>>5), b = (size_t)(m&31);
        const float* src = x + ((b*2048 + t)<<9) + kb*128 + c8;
        f32x4 v0 = *(const f32x4*)src, v1 = *(const f32x4*)(src+4);
        unsigned short* d = &At[row*136 + c8];
        d[0]=f2bf(v0[0]); d[1]=f2bf(v0[1]); d[2]=f2bf(v0[2]); d[3]=f2bf(v0[3]);
        d[4]=f2bf(v1[0]); d[5]=f2bf(v1[1]); d[6]=f2bf(v1[2]); d[7]=f2bf(v1[3]);
      }
      {
        const float* src = Wih + (size_t)(n0+row)*512 + kb*128 + c8;
        f32x4 v0 = *(const f32x4*)src, v1 = *(const f32x4*)(src+4);
        unsigned short* d = &Bt[row*136 + c8];
        d[0]=f2bf(v0[0]); d[1]=f2bf(v0[1]); d[2]=f2bf(v0[2]); d[3]=f2bf(v0[3]);
        d[4]=f2bf(v1[0]); d[5]=f2bf(v1[1]); d[6]=f2bf(v1[2]); d[7]=f2bf(v1[3]);
      }
    }
    __syncthreads();
    #pragma unroll
    for (int ks=0; ks<4; ++ks){
      s16x8 af0 = *(const s16x8*)&At[(mbase+   l15)*136 + ks*32 + l4*8];
      s16x8 af1 = *(const s16x8*)&At[(mbase+16+l15)*136 + ks*32 + l4*8];
      s16x8 bf0 = *(const s16x8*)&Bt[(nbase+   l15)*136 + ks*32 + l4*8];
      s16x8 bf1 = *(const s16x8*)&Bt[(nbase+16+l15)*136 + ks*32 + l4*8];
      acc[0][0] = MFMA16(af0,bf0,acc[0][0]);
      acc[0][1] = MFMA16(af0,bf1,acc[0][1]);
      acc[1][0] = MFMA16(af1,bf0,acc[1][0]);
      acc[1][1] = MFMA16(af1,bf1,acc[1][1]);
    }
    __syncthreads();
  }
  #pragma unroll
  for (int ni=0; ni<2; ++ni){
    int col = n0 + nbase + ni*16 + l15;
    float bias = bih[col] + bhh[col];
    #pragma unroll
    for (int mi=0; mi<2; ++mi){
      #pragma unroll
      for (int r=0; r<4; ++r){
        int mrow = m0 + mbase + mi*16 + l4*4 + r;
        xp[(size_t)mrow*2048 + col] = f2bf(acc[mi][ni][r] + bias);
      }
    }
  }
}

// ---------------- Phase 2: recurrence (tagged exchange, probe+verify) --------
__global__ __launch_bounds__(256,1) void lstm_p2(
    const unsigned short* __restrict__ xp, const float* __restrict__ Whh,
    u32* __restrict__ H32, float* __restrict__ cst,
    float* __restrict__ out, int t0)
{
  const int k = blockIdx.x;
  const int tid = threadIdx.x;
  const int lane = tid & 63, w = tid >> 6;
  const int l15 = lane & 15, l4 = lane >> 4;
  const int g = l15 & 3;                        // lane's gate
  const int U = k*16 + w*4 + (l15 >> 2);        // lane's global hidden unit
  const int gcol = g*512 + U;                   // xp column of this gate-row
  const int q = g;                              // quad member -> 2 publish batches
  const int bq = (q>>1)*16 + l4*4 + (q&1)*2;

  __shared__ __align__(16) char HlBuf[2*32*1024];

  // W_hh B-fragments: wave's 16 gate rows, n=l15 -> W row g*512+U
  s16x8 wf[16];
  {
    const float* wr = Whh + (size_t)(g*512 + U)*512;
    #pragma unroll
    for (int ks=0; ks<16; ++ks){
      const float* s = wr + ks*32 + l4*8;
      f32x4 v0 = *(const f32x4*)s, v1 = *(const f32x4*)(s+4);
      s16x8 tt;
      tt[0]=(short)f2bf(v0[0]); tt[1]=(short)f2bf(v0[1]);
      tt[2]=(short)f2bf(v0[2]); tt[3]=(short)f2bf(v0[3]);
      tt[4]=(short)f2bf(v1[0]); tt[5]=(short)f2bf(v1[1]);
      tt[6]=(short)f2bf(v1[2]); tt[7]=(short)f2bf(v1[3]);
      wf[ks] = tt;
    }
  }

  // c-state restore (quad-redundant)
  float c[2][4];
  #pragma unroll
  for (int mt2=0; mt2<2; ++mt2)
    #pragma unroll
    for (int r=0; r<4; ++r)
      c[mt2][r] = cst[(size_t)(mt2*16 + l4*4 + r)*512 + U];

  for (int tt=0; tt<CHUNK; ++tt){
    const int t = t0 + tt;
    const u32 tagc = (u32)t, tagn = (u32)(t+1);
    const u32* Hs = H32 + (size_t)(t & 3)*16384;
    u32*       Hd = H32 + (size_t)((t+1) & 3)*16384;
    char* Hl = HlBuf + (size_t)(t & 1)*32768;

    // xp gate inputs (issue early; consumed at gate stage)
    float xg[2][4];
    #pragma unroll
    for (int mt2=0; mt2<2; ++mt2)
      #pragma unroll
      for (int r=0; r<4; ++r)
        xg[mt2][r] = bf2f(xp[(size_t)(tt*32 + mt2*16 + l4*4 + r)*2048 + gcol]);

    // probe: one sentinel per producer block (batch 0, unit 16*lane)
    if (w == 0){
      u32 v;
      do {
        v = (lane < NBLK)
          ? __hip_atomic_load(&Hs[lane<<4], __ATOMIC_RELAXED, __HIP_MEMORY_SCOPE_AGENT)
          : tagc;
      } while (__any((v & 0xffffu) != tagc));
    }
    __syncthreads();

    // bulk fetch + verify + swizzled LDS stage (one row per wave per iter)
    for (;;){
      __builtin_amdgcn_fence(__ATOMIC_ACQUIRE, "agent");
      u32 bad = 0;
      #pragma unroll
      for (int j=0; j<8; ++j){
        const int r = w*8 + j;
        const u32* rp = Hs + r*512 + lane*8;
        u32x4 F0 = *(const u32x4*)rp;
        u32x4 F1 = *(const u32x4*)(rp + 4);
        bad |= (F0[0]^tagc) | (F0[1]^tagc) | (F0[2]^tagc) | (F0[3]^tagc);
        bad |= (F1[0]^tagc) | (F1[1]^tagc) | (F1[2]^tagc) | (F1[3]^tagc);
        u32x4 o;
        o[0] = (F0[0]>>16) | (F0[1] & 0xffff0000u);
        o[1] = (F0[2]>>16) | (F0[3] & 0xffff0000u);
        o[2] = (F1[0]>>16) | (F1[1] & 0xffff0000u);
        o[3] = (F1[2]>>16) | (F1[3] & 0xffff0000u);
        *(u32x4*)(Hl + (r<<10) + ((lane*16) ^ ((r&7)<<4))) = o;
      }
      bad &= 0xffffu;
      if (__syncthreads_count((int)(bad != 0)) == 0) break;
    }

    // z = h_t @ Wslice^T : 2 m-tiles x 16 ks, A from swizzled LDS
    f32x4 z[2];
    #pragma unroll
    for (int mt2=0; mt2<2; ++mt2){
      const int row = mt2*16 + l15;
      const int swz = (row&7)<<4, rb = row<<10;
      f32x4 acc = (f32x4){0.f,0.f,0.f,0.f};
      #pragma unroll
      for (int ks=0; ks<16; ++ks){
        int cb = ks*64 + l4*16;
        s16x8 af = *(const s16x8*)(Hl + (rb | (cb ^ swz)));
        acc = MFMA16(af, wf[ks], acc);
      }
      z[mt2] = acc;
    }

    // gates: quad shfl exchange (lane holds gate g of its unit, 8 batches)
    float hv[2][4];
    #pragma unroll
    for (int mt2=0; mt2<2; ++mt2){
      #pragma unroll
      for (int r=0; r<4; ++r){
        float v = z[mt2][r] + xg[mt2][r];
        float vi = __shfl_xor(v, g    );
        float vf = __shfl_xor(v, g ^ 1);
        float vg = __shfl_xor(v, g ^ 2);
        float vo = __shfl_xor(v, g ^ 3);
        float ii = sigmoid_(vi), ff = sigmoid_(vf);
        float gg = tanh_(vg),    oo = sigmoid_(vo);
        float cc = ff*c[mt2][r] + ii*gg;
        c[mt2][r] = cc;
        hv[mt2][r] = oo * tanh_(cc);
      }
    }

    // publish h_{t+1}: 2 tagged words per lane, drain-free
    {
      float ha0 = (q&1) ? hv[0][2] : hv[0][0];
      float ha1 = (q&1) ? hv[0][3] : hv[0][1];
      float hb0 = (q&1) ? hv[1][2] : hv[1][0];
      float hb1 = (q&1) ? hv[1][3] : hv[1][1];
      float h0 = (q>>1) ? hb0 : ha0;
      float h1 = (q>>1) ? hb1 : ha1;
      u32 w0 = ((u32)f2bf(h0) << 16) | tagn;
      u32 w1 = ((u32)f2bf(h1) << 16) | tagn;
      __hip_atomic_store(&Hd[(size_t)(bq  )*512 + U], w0,
                         __ATOMIC_RELAXED, __HIP_MEMORY_SCOPE_AGENT);
      __hip_atomic_store(&Hd[(size_t)(bq+1)*512 + U], w1,
                         __ATOMIC_RELAXED, __HIP_MEMORY_SCOPE_AGENT);
      if (t == T_FULL-1){
        out[(size_t)(bq  )*512 + U] = h0;
        out[(size_t)(bq+1)*512 + U] = h1;
      }
    }
  }

  // c-state save (lane's 2 assigned batches)
  {
    float ca0 = (q&1) ? c[0][2] : c[0][0];
    float ca1 = (q&1) ? c[0][3] : c[0][1];
    float cb0 = (q&1) ? c[1][2] : c[1][0];
    float cb1 = (q&1) ? c[1][3] : c[1][1];
    float c0s = (q>>1) ? cb0 : ca0;
    float c1s = (q>>1) ? cb1 : ca1;
    cst[(size_t)(bq  )*512 + U] = c0s;
    cst[(size_t)(bq+1)*512 + U] = c1s;
  }
}

// ---------------- launch ----------------
extern "C" void kernel_launch(void* const* d_in, const int* in_sizes, int n_in,
                              void* d_out, int out_size, void* d_ws, size_t ws_size,
                              hipStream_t stream)
{
  const float* x   = (const float*)d_in[0];
  const float* Wih = (const float*)d_in[1];
  const float* Whh = (const float*)d_in[2];
  const float* bih = (const float*)d_in[3];
  const float* bhh = (const float*)d_in[4];
  float* out = (float*)d_out;

  char* ws = (char*)d_ws;
  const size_t XP_BYTES = (size_t)CHUNK*32*2048*2;                 // 33,554,432
  unsigned short* xp  = (unsigned short*)ws;
  u32*            H32 = (u32*)(ws + XP_BYTES);                     // 4*64KB = 262144
  float*          cst = (float*)(ws + XP_BYTES + 262144);          // 64KB

  // zero tagged H (tag0 == h_0 == 0) + c-state; every launch (replay-safe)
  (void)hipMemsetAsync(H32, 0, 262144 + 65536, stream);

  for (int c=0; c<NCHUNK; ++c){
    int t0 = c*CHUNK;
    lstm_p1<<<dim3(32, CHUNK*32/64), 256, 0, stream>>>(x, Wih, bih, bhh, xp, t0);
    lstm_p2<<<NBLK, 256, 0, stream>>>(xp, Whh, H32, cst, out, t0);
  }
}

// Round 7
// 12944.025 us; speedup vs baseline: 1.9298x; 1.0538x over previous
//
#include <hip/hip_runtime.h>

// LSTM B=32 T=2048 I=H=512. out = h_T [1,32,512] f32.
// p1: x_proj chunk GEMM (bf16 MFMA) -> xp[t_local*32+b][4H] bf16 (bias folded).
// p2: 128 autonomous single-wave blocks, no LDS, no barriers. Wave (c,s):
//   chain c (batches c*16..+16), slice s (units s*8..+8, gate rows unit*4+gate).
//   W_hh frags resident (128 VGPR). Per step: poll 64 per-wave flags of own
//   chain -> acquire fence -> fetch 16KB H directly into MFMA A-frags (64 VGPR)
//   -> 32 MFMA -> quad-shfl gates -> paired-u32 publish -> vmcnt(0) -> flag.
//   Two chains run concurrently on disjoint CUs: full-step ~ one chain period.

#define T_FULL 2048
#define CHUNK  256
#define NCHUNK 8

typedef float  f32x4 __attribute__((ext_vector_type(4)));
typedef short  s16x8 __attribute__((ext_vector_type(8)));
typedef unsigned int u32;

#define MFMA16(a,b,c) __builtin_amdgcn_mfma_f32_16x16x32_bf16((a),(b),(c),0,0,0)

__device__ inline unsigned short f2bf(float f){
  unsigned u = __builtin_bit_cast(unsigned, f);
  u += 0x7fffu + ((u>>16)&1u);          // RNE
  return (unsigned short)(u>>16);
}
__device__ inline float bf2f(unsigned short s){
  unsigned u = ((unsigned)s)<<16;
  return __builtin_bit_cast(float, u);
}
__device__ inline float sigmoid_(float x){
  x = fminf(fmaxf(x,-30.f),30.f);
  return 1.f/(1.f + __expf(-x));
}
__device__ inline float tanh_(float x){
  x = fminf(fmaxf(x,-15.f),15.f);
  float e = __expf(2.f*x);
  return (e-1.f)/(e+1.f);
}

// ---------------- Phase 1: x_proj chunk GEMM ----------------
__global__ __launch_bounds__(256) void lstm_p1(
    const float* __restrict__ x, const float* __restrict__ Wih,
    const float* __restrict__ bih, const float* __restrict__ bhh,
    unsigned short* __restrict__ xp, int t0)
{
  __shared__ __align__(16) unsigned short At[64*136];
  __shared__ __align__(16) unsigned short Bt[64*136];
  const int tid = threadIdx.x, lane = tid&63, w = tid>>6;
  const int l15 = lane&15, l4 = lane>>4;
  const int n0 = blockIdx.x*64, m0 = blockIdx.y*64;
  const int mbase = (w&1)*32, nbase = (w>>1)*32;

  f32x4 acc[2][2];
  #pragma unroll
  for (int mi=0; mi<2; ++mi)
    #pragma unroll
    for (int ni=0; ni<2; ++ni)
      acc[mi][ni] = (f32x4){0.f,0.f,0.f,0.f};

  for (int kb=0; kb<4; ++kb){
    #pragma unroll
    for (int it=0; it<4; ++it){
      int grp = it*256 + tid;            // 0..1023
      int row = grp>>4, c8 = (grp&15)*8; // 16 groups of 8 per row
      {
        int m = m0 + row;
        size_t t = (size_t)t0 + (m>>5), b = (size_t)(m&31);
        const float* src = x + ((b*2048 + t)<<9) + kb*128 + c8;
        f32x4 v0 = *(const f32x4*)src, v1 = *(const f32x4*)(src+4);
        unsigned short* d = &At[row*136 + c8];
        d[0]=f2bf(v0[0]); d[1]=f2bf(v0[1]); d[2]=f2bf(v0[2]); d[3]=f2bf(v0[3]);
        d[4]=f2bf(v1[0]); d[5]=f2bf(v1[1]); d[6]=f2bf(v1[2]); d[7]=f2bf(v1[3]);
      }
      {
        const float* src = Wih + (size_t)(n0+row)*512 + kb*128 + c8;
        f32x4 v0 = *(const f32x4*)src, v1 = *(const f32x4*)(src+4);
        unsigned short* d = &Bt[row*136 + c8];
        d[0]=f2bf(v0[0]); d[1]=f2bf(v0[1]); d[2]=f2bf(v0[2]); d[3]=f2bf(v0[3]);
        d[4]=f2bf(v1[0]); d[5]=f2bf(v1[1]); d[6]=f2bf(v1[2]); d[7]=f2bf(v1[3]);
      }
    }
    __syncthreads();
    #pragma unroll
    for (int ks=0; ks<4; ++ks){
      s16x8 af0 = *(const s16x8*)&At[(mbase+   l15)*136 + ks*32 + l4*8];
      s16x8 af1 = *(const s16x8*)&At[(mbase+16+l15)*136 + ks*32 + l4*8];
      s16x8 bf0 = *(const s16x8*)&Bt[(nbase+   l15)*136 + ks*32 + l4*8];
      s16x8 bf1 = *(const s16x8*)&Bt[(nbase+16+l15)*136 + ks*32 + l4*8];
      acc[0][0] = MFMA16(af0,bf0,acc[0][0]);
      acc[0][1] = MFMA16(af0,bf1,acc[0][1]);
      acc[1][0] = MFMA16(af1,bf0,acc[1][0]);
      acc[1][1] = MFMA16(af1,bf1,acc[1][1]);
    }
    __syncthreads();
  }
  #pragma unroll
  for (int ni=0; ni<2; ++ni){
    int col = n0 + nbase + ni*16 + l15;
    float bias = bih[col] + bhh[col];
    #pragma unroll
    for (int mi=0; mi<2; ++mi){
      #pragma unroll
      for (int r=0; r<4; ++r){
        int mrow = m0 + mbase + mi*16 + l4*4 + r;
        xp[(size_t)mrow*2048 + col] = f2bf(acc[mi][ni][r] + bias);
      }
    }
  }
}

// ---------------- Phase 2: autonomous per-wave recurrence ----------------
// Hbuf: [chain 2][slot 4][batch 16][unit 512] bf16 (8KB-u16 = 16KB per slot).
// flag[(c*64+s)*16]: u32, value = latest step published by wave (c,s).
__global__ __launch_bounds__(64,1) void lstm_p2(
    const unsigned short* __restrict__ xp, const float* __restrict__ Whh,
    unsigned short* __restrict__ Hbuf, float* __restrict__ cst,
    u32* __restrict__ flag, float* __restrict__ out, int t0)
{
  const int lane = threadIdx.x;
  const int c = blockIdx.x >> 6, s = blockIdx.x & 63;
  const int l15 = lane & 15, l4 = lane >> 4;
  const int g = l15 & 3, uq = l15 >> 2;
  const int u0 = s*8 + uq, u1 = u0 + 4;

  // W_hh B-fragments for this wave's 32 gate rows (2 n-tiles x 16 k-steps)
  s16x8 wf0[16], wf1[16];
  {
    const float* w0 = Whh + (size_t)(g*512 + u0)*512 + l4*8;
    const float* w1 = Whh + (size_t)(g*512 + u1)*512 + l4*8;
    #pragma unroll
    for (int ks=0; ks<16; ++ks){
      f32x4 a0 = *(const f32x4*)(w0 + ks*32), b0 = *(const f32x4*)(w0 + ks*32 + 4);
      f32x4 a1 = *(const f32x4*)(w1 + ks*32), b1 = *(const f32x4*)(w1 + ks*32 + 4);
      s16x8 t0v, t1v;
      t0v[0]=(short)f2bf(a0[0]); t0v[1]=(short)f2bf(a0[1]);
      t0v[2]=(short)f2bf(a0[2]); t0v[3]=(short)f2bf(a0[3]);
      t0v[4]=(short)f2bf(b0[0]); t0v[5]=(short)f2bf(b0[1]);
      t0v[6]=(short)f2bf(b0[2]); t0v[7]=(short)f2bf(b0[3]);
      t1v[0]=(short)f2bf(a1[0]); t1v[1]=(short)f2bf(a1[1]);
      t1v[2]=(short)f2bf(a1[2]); t1v[3]=(short)f2bf(a1[3]);
      t1v[4]=(short)f2bf(b1[0]); t1v[5]=(short)f2bf(b1[1]);
      t1v[6]=(short)f2bf(b1[2]); t1v[7]=(short)f2bf(b1[3]);
      wf0[ks] = t0v; wf1[ks] = t1v;
    }
  }

  // c-state restore (quad-redundant: all 4 batches per unit)
  float c0[4], c1[4];
  #pragma unroll
  for (int r=0; r<4; ++r){
    c0[r] = cst[(size_t)(c*16 + l4*4 + r)*512 + u0];
    c1[r] = cst[(size_t)(c*16 + l4*4 + r)*512 + u1];
  }

  for (int tt=0; tt<CHUNK; ++tt){
    const int t = t0 + tt;

    // xp gate inputs (prefetch; off critical path)
    float xg0[4], xg1[4];
    {
      const unsigned short* xrow = xp + (size_t)(tt*32 + c*16)*2048 + g*512;
      #pragma unroll
      for (int r=0; r<4; ++r){
        xg0[r] = bf2f(xrow[(size_t)(l4*4+r)*2048 + u0]);
        xg1[r] = bf2f(xrow[(size_t)(l4*4+r)*2048 + u1]);
      }
    }

    // poll own chain's 64 per-wave flags (own lane trivially ready)
    {
      u32 v;
      do {
        v = (lane == s) ? (u32)t
          : __hip_atomic_load(&flag[(u32)((c<<6) | lane) << 4],
                              __ATOMIC_RELAXED, __HIP_MEMORY_SCOPE_AGENT);
      } while (__any(v < (u32)t));
    }
    __builtin_amdgcn_fence(__ATOMIC_ACQUIRE, "agent");

    // fetch H(t) directly into A-fragments: 16 x 16B per lane
    s16x8 hf[16];
    {
      const unsigned short* Hs = Hbuf + (size_t)((c<<2) | (t&3))*8192 + l15*512 + l4*8;
      #pragma unroll
      for (int ks=0; ks<16; ++ks)
        hf[ks] = *(const s16x8*)(Hs + ks*32);
    }

    // z = H @ Wslice^T : 2 n-tiles x 16 k-steps
    f32x4 acc0 = (f32x4){0.f,0.f,0.f,0.f};
    f32x4 acc1 = (f32x4){0.f,0.f,0.f,0.f};
    #pragma unroll
    for (int ks=0; ks<16; ++ks){
      acc0 = MFMA16(hf[ks], wf0[ks], acc0);
      acc1 = MFMA16(hf[ks], wf1[ks], acc1);
    }

    // gates: quad shfl exchange (lane holds gate g of its units, 4 batches)
    float hv0[4], hv1[4];
    #pragma unroll
    for (int r=0; r<4; ++r){
      float v = acc0[r] + xg0[r];
      float vi = __shfl_xor(v, g    );
      float vf = __shfl_xor(v, g ^ 1);
      float vg = __shfl_xor(v, g ^ 2);
      float vo = __shfl_xor(v, g ^ 3);
      float ii = sigmoid_(vi), ff = sigmoid_(vf), gg = tanh_(vg), oo = sigmoid_(vo);
      float cc = ff*c0[r] + ii*gg; c0[r] = cc; hv0[r] = oo*tanh_(cc);
      v = acc1[r] + xg1[r];
      vi = __shfl_xor(v, g    );
      vf = __shfl_xor(v, g ^ 1);
      vg = __shfl_xor(v, g ^ 2);
      vo = __shfl_xor(v, g ^ 3);
      ii = sigmoid_(vi); ff = sigmoid_(vf); gg = tanh_(vg); oo = sigmoid_(vo);
      cc = ff*c1[r] + ii*gg; c1[r] = cc; hv1[r] = oo*tanh_(cc);
    }

    // static g-select of this lane's publish values (batch l4*4+g)
    float hsel0 = (g&1) ? ((g&2) ? hv0[3] : hv0[1]) : ((g&2) ? hv0[2] : hv0[0]);
    float hsel1 = (g&1) ? ((g&2) ? hv1[3] : hv1[1]) : ((g&2) ? hv1[2] : hv1[0]);

    // publish h(t+1): pair units (u,u+1) into one u32; uq-even lanes store
    {
      unsigned short* Hd = Hbuf + (size_t)((c<<2) | ((t+1)&3))*8192;
      u32 hb0 = f2bf(hsel0), hb1 = f2bf(hsel1);
      u32 o0 = (u32)__shfl_xor((int)hb0, 4);
      u32 o1 = (u32)__shfl_xor((int)hb1, 4);
      if ((uq & 1) == 0){
        __hip_atomic_store((u32*)(Hd + (l4*4+g)*512 + u0), hb0 | (o0<<16),
                           __ATOMIC_RELAXED, __HIP_MEMORY_SCOPE_AGENT);
        __hip_atomic_store((u32*)(Hd + (l4*4+g)*512 + u1), hb1 | (o1<<16),
                           __ATOMIC_RELAXED, __HIP_MEMORY_SCOPE_AGENT);
      }
      if (t == T_FULL-1){
        out[(size_t)(c*16 + l4*4 + g)*512 + u0] = hsel0;
        out[(size_t)(c*16 + l4*4 + g)*512 + u1] = hsel1;
      }
    }

    // drain own stores, then publish flag
    asm volatile("s_waitcnt vmcnt(0)" ::: "memory");
    if (lane == 0)
      __hip_atomic_store(&flag[(u32)((c<<6) | s) << 4], (u32)(t+1),
                         __ATOMIC_RELAXED, __HIP_MEMORY_SCOPE_AGENT);
  }

  // c-state save (lane's batch l4*4+g, both units)
  {
    float cs0 = (g&1) ? ((g&2) ? c0[3] : c0[1]) : ((g&2) ? c0[2] : c0[0]);
    float cs1 = (g&1) ? ((g&2) ? c1[3] : c1[1]) : ((g&2) ? c1[2] : c1[0]);
    cst[(size_t)(c*16 + l4*4 + g)*512 + u0] = cs0;
    cst[(size_t)(c*16 + l4*4 + g)*512 + u1] = cs1;
  }
}

// ---------------- launch ----------------
extern "C" void kernel_launch(void* const* d_in, const int* in_sizes, int n_in,
                              void* d_out, int out_size, void* d_ws, size_t ws_size,
                              hipStream_t stream)
{
  const float* x   = (const float*)d_in[0];
  const float* Wih = (const float*)d_in[1];
  const float* Whh = (const float*)d_in[2];
  const float* bih = (const float*)d_in[3];
  const float* bhh = (const float*)d_in[4];
  float* out = (float*)d_out;

  char* ws = (char*)d_ws;
  const size_t XP_BYTES = (size_t)CHUNK*32*2048*2;                  // 33,554,432
  unsigned short* xp   = (unsigned short*)ws;
  unsigned short* Hbuf = (unsigned short*)(ws + XP_BYTES);          // 2*4*16KB = 131072
  float*          cst  = (float*)(ws + XP_BYTES + 131072);          // 64KB
  u32*            flag = (u32*)(ws + XP_BYTES + 131072 + 65536);    // 128*64B = 8KB

  // zero Hbuf (h_0 = 0) + c-state + flags; every launch (replay-safe)
  (void)hipMemsetAsync(Hbuf, 0, 131072 + 65536 + 8192, stream);

  for (int c=0; c<NCHUNK; ++c){
    int t0 = c*CHUNK;
    lstm_p1<<<dim3(32, CHUNK*32/64), 256, 0, stream>>>(x, Wih, bih, bhh, xp, t0);
    lstm_p2<<<128, 64, 0, stream>>>(xp, Whh, Hbuf, cst, flag, out, t0);
  }
}